// Round 6
// baseline (145.085 us; speedup 1.0000x reference)
//
#include <hip/hip_runtime.h>
#include <math.h>

#define DD 160
#define HH 192
#define WW 160
#define TW 16          // per-wave tile width
#define TH 4           // per-wave tile height
#define BW 32          // block tile width  (2x2 waves)
#define BH 8           // block tile height
#define TD 8           // slices per block
#define HW (HH * WW)
#define NVOX (DD * HW)
#define HTW 18         // halo cols
#define HTH 6          // halo rows
#define LSTR 17        // LDS row stride — odd => 2-way-max bank aliasing (free)
#define HALO (HTH * HTW)   // 108
#define WBUF (HTH * LSTR)  // 102 floats per [wave][parity][field]

// atan via odd minimax poly on [0,1] + rcp range reduction; max err ~1e-5 rad
__device__ __forceinline__ float atan_fast(float r) {
    float ar = fabsf(r);
    float inv = __builtin_amdgcn_rcpf(ar);
    bool big = ar > 1.0f;
    float x = big ? inv : ar;
    float x2 = x * x;
    float p = fmaf(x2, fmaf(x2, fmaf(x2, fmaf(x2, fmaf(x2,
              -0.0117212f, 0.05265332f), -0.11643287f), 0.19354346f),
              -0.33262347f), 0.99997726f);
    p *= x;
    float res = big ? (1.57079632679489662f - p) : p;
    return copysignf(res, r);
}

// 4 independent waves per block, each with a private LDS region and a
// wave-local software pipeline — NO __syncthreads in the main loop (in-order
// per-wave DS ops + compiler waitcnt give correctness; round-5 structure).
// Packing 4 waves/WG escapes the per-CU workgroup-slot limit that capped
// round 5's occupancy at ~30%.
__global__ __launch_bounds__(256) void demons_ori_kernel(
    const float* __restrict__ Mv, const float* __restrict__ Sv,
    const float* __restrict__ flow, float* __restrict__ out)
{
    __shared__ float buf[4][2][2][WBUF];   // [wave][parity][field][h*LSTR+w]
    __shared__ float redbuf[4];

    const int tid = threadIdx.x;
    const int wid = tid >> 6;
    const int lane = tid & 63;
    const int tw = lane & 15;
    const int th = lane >> 4;
    const int w0 = blockIdx.x * BW + (wid & 1) * TW;
    const int h0 = blockIdx.y * BH + (wid >> 1) * TH;
    const int d0 = blockIdx.z * TD;

    // slice-invariant staging slots: slot0 = lane, slot1 = lane+64 (if <108)
    const bool has1 = (lane < HALO - 64);
    int idx0, gb0, idx1 = 0, gb1 = 0;
    bool ok0, ok1 = false;
    {
        int i = lane;
        int hh = i / HTW, ww = i - HTW * hh;
        int gh = h0 + hh - 1, gw = w0 + ww - 1;
        idx0 = hh * LSTR + ww;
        ok0 = (gh >= 0 && gh < HH && gw >= 0 && gw < WW);
        gb0 = gh * WW + gw;
        if (has1) {
            i = lane + 64;
            hh = i / HTW; ww = i - HTW * hh;
            gh = h0 + hh - 1; gw = w0 + ww - 1;
            idx1 = hh * LSTR + ww;
            ok1 = (gh >= 0 && gh < HH && gw >= 0 && gw < WW);
            gb1 = gh * WW + gw;
        }
    }

    // two prefetch register sets (distance-2 pipeline) — named scalars only
    float aS0 = 0.f, aM0 = 0.f, aS1 = 0.f, aM1 = 0.f;   // set A
    float bS0 = 0.f, bM0 = 0.f, bS1 = 0.f, bM1 = 0.f;   // set B

    auto issueA = [&](int d) {
        const bool din = (d >= 0) && (d < DD);
        const size_t base = (size_t)d * HW;
        aS0 = (din && ok0) ? Sv[base + gb0] : 0.f;
        aM0 = (din && ok0) ? Mv[base + gb0] : 0.f;
        aS1 = (din && ok1) ? Sv[base + gb1] : 0.f;
        aM1 = (din && ok1) ? Mv[base + gb1] : 0.f;
    };
    auto issueB = [&](int d) {
        const bool din = (d >= 0) && (d < DD);
        const size_t base = (size_t)d * HW;
        bS0 = (din && ok0) ? Sv[base + gb0] : 0.f;
        bM0 = (din && ok0) ? Mv[base + gb0] : 0.f;
        bS1 = (din && ok1) ? Sv[base + gb1] : 0.f;
        bM1 = (din && ok1) ? Mv[base + gb1] : 0.f;
    };
    auto commitA = [&](int d) {
        float* __restrict__ bS = &buf[wid][d & 1][0][0];
        float* __restrict__ bM = &buf[wid][d & 1][1][0];
        bS[idx0] = aS0; bM[idx0] = aM0;
        if (has1) { bS[idx1] = aS1; bM[idx1] = aM1; }
    };
    auto commitB = [&](int d) {
        float* __restrict__ bS = &buf[wid][d & 1][0][0];
        float* __restrict__ bM = &buf[wid][d & 1][1][0];
        bS[idx0] = bS0; bM[idx0] = bM0;
        if (has1) { bS[idx1] = bS1; bM[idx1] = bM1; }
    };

    const int rb = th * LSTR + tw;   // center voxel at (th+1, tw+1)
    // separable in-plane partials: pq[f] = {Px, Py, B, center}
    auto partials = [&](int par, float pq[2][4]) {
        #pragma unroll
        for (int f = 0; f < 2; ++f) {
            const float* __restrict__ b = &buf[wid][par][f][0];
            const float* r0 = b + rb;
            const float* r1 = r0 + LSTR;
            const float* r2 = r1 + LSTR;
            float v00 = r0[0], v01 = r0[1], v02 = r0[2];
            float v10 = r1[0], v11 = r1[1], v12 = r1[2];
            float v20 = r2[0], v21 = r2[1], v22 = r2[2];
            pq[f][0] = (v02 + 2.f * v12 + v22) - (v00 + 2.f * v10 + v20);
            pq[f][1] = (v20 + 2.f * v21 + v22) - (v00 + 2.f * v01 + v02);
            pq[f][2] = (v00 + v01 + v02) + 2.f * (v10 + v11 + v12)
                     + (v20 + v21 + v22);
            pq[f][3] = v11;
        }
    };

    float Pm[2][4], P0[2][4], Pp[2][4];

    // ---- warmup: distance-2 pipeline fill ----
    issueA(d0 - 1);
    issueB(d0);
    commitA(d0 - 1);             // only long exposed vmcnt wait
    partials((d0 - 1) & 1, Pm);
    issueA(d0 + 1);              // consumed at loop dd=0
    commitB(d0);
    partials(d0 & 1, P0);
    issueB(d0 + 2);              // consumed at loop dd=1

    const size_t voff0 = (size_t)(h0 + th) * WW + (w0 + tw);
    // flow prefetch sets (distance 2): set0 for even dd, set1 for odd dd
    float fx0 = flow[(size_t)d0 * HW + voff0];
    float fy0 = flow[(size_t)NVOX + (size_t)d0 * HW + voff0];
    float fz0 = flow[2 * (size_t)NVOX + (size_t)d0 * HW + voff0];
    float fx1 = flow[(size_t)(d0 + 1) * HW + voff0];
    float fy1 = flow[(size_t)NVOX + (size_t)(d0 + 1) * HW + voff0];
    float fz1 = flow[2 * (size_t)NVOX + (size_t)(d0 + 1) * HW + voff0];

    float lsum = 0.f;

    #pragma unroll
    for (int dd = 0; dd < TD; ++dd) {
        const int d = d0 + dd;
        // commit loads issued 2 stages ago; re-issue same set for d+3
        if ((dd & 1) == 0) {
            commitA(d + 1);
            if (dd <= TD - 3) issueA(d + 3);
        } else {
            commitB(d + 1);
            if (dd <= TD - 3) issueB(d + 3);
        }
        partials((d + 1) & 1, Pp);

        float idf = P0[1][3] - P0[0][3];
        float i2 = idf * idf + 1e-10f;
        float gxS = Pm[0][0] + P0[0][0] + Pp[0][0];
        float gyS = Pm[0][1] + P0[0][1] + Pp[0][1];
        float gzS = Pp[0][2] - Pm[0][2];
        float gxM = Pm[1][0] + P0[1][0] + Pp[1][0];
        float gyM = Pm[1][1] + P0[1][1] + Pp[1][1];
        float gzM = Pp[1][2] - Pm[1][2];
        float denS = gxS * gxS + gyS * gyS + gzS * gzS + i2;
        float denM = gxM * gxM + gyM * gyM + gzM * gzM + i2;
        float rS = __builtin_amdgcn_rcpf(denS);
        float rM = __builtin_amdgcn_rcpf(denM);
        float Ux = idf * (gxS * rS + gxM * rM);
        float Uy = idf * (gyS * rS + gyM * rM);
        float Uz = idf * (gzS * rS + gzM * rM);
        float rz = __builtin_amdgcn_rcpf(Uz + 1e-10f);
        float dxz = atan_fast(Ux * rz);
        float dyz = atan_fast(Uy * rz);

        float ffx = (dd & 1) ? fx1 : fx0;
        float ffy = (dd & 1) ? fy1 : fy0;
        float ffz = (dd & 1) ? fz1 : fz0;
        float rf = __builtin_amdgcn_rcpf(ffz + 1e-10f);
        float fxz = atan_fast(ffx * rf);
        float fyz = atan_fast(ffy * rf);

        float e1 = fxz - dxz;
        float e2 = fyz - dyz;
        lsum += e1 * e1 + e2 * e2;

        // reload this flow set for slice d+2 (consumed at dd+2)
        if (dd <= TD - 3) {
            size_t foff = (size_t)(d + 2) * HW + voff0;
            if ((dd & 1) == 0) {
                fx0 = flow[foff];
                fy0 = flow[(size_t)NVOX + foff];
                fz0 = flow[2 * (size_t)NVOX + foff];
            } else {
                fx1 = flow[foff];
                fy1 = flow[(size_t)NVOX + foff];
                fz1 = flow[2 * (size_t)NVOX + foff];
            }
        }

        #pragma unroll
        for (int f = 0; f < 2; ++f)
            #pragma unroll
            for (int q = 0; q < 4; ++q) {
                Pm[f][q] = P0[f][q];
                P0[f][q] = Pp[f][q];
            }
    }

    // wave shuffle reduce -> per-wave LDS slot -> one atomic per block
    #pragma unroll
    for (int o = 32; o > 0; o >>= 1)
        lsum += __shfl_down(lsum, o, 64);
    if (lane == 0)
        redbuf[wid] = lsum;
    __syncthreads();
    if (tid == 0) {
        float s = redbuf[0] + redbuf[1] + redbuf[2] + redbuf[3];
        atomicAdd(out, s * (1.0f / (float)NVOX));
    }
}

extern "C" void kernel_launch(void* const* d_in, const int* in_sizes, int n_in,
                              void* d_out, int out_size, void* d_ws, size_t ws_size,
                              hipStream_t stream) {
    const float* Mv   = (const float*)d_in[0];
    const float* Sv   = (const float*)d_in[1];
    const float* flow = (const float*)d_in[2];
    float* out = (float*)d_out;

    hipMemsetAsync(out, 0, sizeof(float), stream);

    dim3 grid(WW / BW, HH / BH, DD / TD);   // 5 x 24 x 20 = 2400 blocks
    demons_ori_kernel<<<grid, dim3(256), 0, stream>>>(Mv, Sv, flow, out);
}